// Round 3
// baseline (694.115 us; speedup 1.0000x reference)
//
#include <hip/hip_runtime.h>
#include <hip/hip_bf16.h>

// S4D: B=8, L=4096, H=1024, N=32 complex modes. All inputs/outputs float32
// (established empirically rounds 0-2: R1 bf16-read -> NaN proves f32 inputs;
// R2 bf16-write left upper half of d_out zero -> absmax == max|ref| proves f32 output).
//
// y[b,l,h] = gelu( sum_{j<=l} K[h,l-j] u[b,j,h] + D*u ), K[h,m] = 2 Re(sum_n C'_n w_n^m)
// Implemented as a 32-mode complex linear scan, chunked over L (blocked scan:
// local scan -> cross-chunk scan -> re-scan + emit).

#define B_ 8
#define L_ 4096
#define H_ 1024
#define N_ 32

// ---------------- kernel A: per-(h,n) mode constants ----------------
// modes[n*H+h] = (w_r, w_i, g_r, g_i); w = exp(dt*A); g = (2 Re C', -2 Im C');
// C' = (C_r + i C_i)*(w-1)/A.  wLc[n*H+h] = w^(Lc).
__global__ void modes_kernel(const float* __restrict__ log_dt,
                             const float* __restrict__ A_real,
                             const float* __restrict__ A_imag,
                             const float* __restrict__ C_real,
                             const float* __restrict__ C_imag,
                             float4* __restrict__ modes,
                             float2* __restrict__ wLc,
                             int log2Lc) {
    int t = blockIdx.x * blockDim.x + threadIdx.x;
    if (t >= H_ * N_) return;
    int h = t / N_, n = t % N_;
    float dt = expf(log_dt[h]);
    float ar = -expf(A_real[t]);
    float ai = A_imag[t];
    float cr = C_real[t];
    float ci = C_imag[t];
    float dr = ar * dt, di = ai * dt;
    float e = expf(dr);
    float sn, cs;
    sincosf(di, &sn, &cs);
    float wr = e * cs, wi = e * sn;
    // q = (w-1)/A via conj(A)/|A|^2 ; n=0 has ai=0, ar ~ -0.5, safe
    float inv = 1.0f / (ar * ar + ai * ai);
    float nr = wr - 1.0f, ni = wi;
    float qr = (nr * ar + ni * ai) * inv;
    float qi = (ni * ar - nr * ai) * inv;
    float gr = 2.0f * (cr * qr - ci * qi);
    float gi = -2.0f * (cr * qi + ci * qr);
    modes[n * H_ + h] = make_float4(wr, wi, gr, gi);
    float pr = wr, pi2 = wi;
    for (int i = 0; i < log2Lc; ++i) {
        float t2r = pr * pr - pi2 * pi2;
        float t2i = 2.0f * pr * pi2;
        pr = t2r; pi2 = t2i;
    }
    wLc[n * H_ + h] = make_float2(pr, pi2);
}

// ---------------- kernel B: local scan per chunk (zero entry state) ----------------
// thread t = ((b*C + c)*H + h); writes final local state per mode, coalesced over h.
template <int C_>
__global__ __launch_bounds__(256) void scan_local(const float* __restrict__ u,
                                                  const float4* __restrict__ modes,
                                                  float2* __restrict__ states) {
    constexpr int Lc = L_ / C_;
    int t = blockIdx.x * blockDim.x + threadIdx.x;
    int h = t % H_;
    int bc = t / H_;
    int c = bc % C_;
    int b = bc / C_;
    float wr[N_], wi[N_], sr[N_], si[N_];
#pragma unroll
    for (int n = 0; n < N_; ++n) {
        float4 m = modes[n * H_ + h];
        wr[n] = m.x; wi[n] = m.y; sr[n] = 0.0f; si[n] = 0.0f;
    }
    const float* up = u + ((size_t)b * L_ + (size_t)c * Lc) * H_ + h;
    float uv_next = up[0];
    for (int j = 0; j < Lc; ++j) {
        float uv = uv_next;
        int jn = (j + 1 < Lc) ? (j + 1) : 0;  // clamp: avoid OOB prefetch
        uv_next = up[(size_t)jn * H_];
#pragma unroll
        for (int n = 0; n < N_; ++n) {
            float tr = fmaf(wr[n], sr[n], fmaf(-wi[n], si[n], uv));
            float ti = fmaf(wr[n], si[n], wi[n] * sr[n]);
            sr[n] = tr; si[n] = ti;
        }
    }
    float2* sp = states + ((size_t)(b * C_ + c) * N_) * H_ + h;
#pragma unroll
    for (int n = 0; n < N_; ++n) sp[(size_t)n * H_] = make_float2(sr[n], si[n]);
}

// ---------------- kernel C: cross-chunk scan (in place: local-end -> entry) --------
// thread t = ((b*N + n)*H + h).  entry[c] = wLc * entry[c-1] + local_end[c-1]
template <int C_>
__global__ __launch_bounds__(256) void chunk_scan(const float2* __restrict__ wLc,
                                                  float2* __restrict__ states) {
    int t = blockIdx.x * blockDim.x + threadIdx.x;
    int h = t % H_;
    int bn = t / H_;
    int n = bn % N_;
    int b = bn / N_;
    float2 wl = wLc[n * H_ + h];
    float er = 0.0f, ei = 0.0f;
    for (int c = 0; c < C_; ++c) {
        float2* p = states + ((size_t)(b * C_ + c) * N_ + n) * H_ + h;
        float2 le = *p;
        *p = make_float2(er, ei);
        float nr2 = fmaf(wl.x, er, fmaf(-wl.y, ei, le.x));
        float ni2 = fmaf(wl.x, ei, fmaf(wl.y, er, le.y));
        er = nr2; ei = ni2;
    }
}

// ---------------- kernel D: re-scan with entry state, emit gelu(y) ----------------
template <int C_>
__global__ __launch_bounds__(256) void scan_out(const float* __restrict__ u,
                                                const float4* __restrict__ modes,
                                                const float2* __restrict__ states,
                                                const float* __restrict__ Dscal,
                                                float* __restrict__ y) {
    constexpr int Lc = L_ / C_;
    int t = blockIdx.x * blockDim.x + threadIdx.x;
    int h = t % H_;
    int bc = t / H_;
    int c = bc % C_;
    int b = bc / C_;
    float Dv = Dscal[0];
    float wr[N_], wi[N_], gr[N_], gi[N_], sr[N_], si[N_];
#pragma unroll
    for (int n = 0; n < N_; ++n) {
        float4 m = modes[n * H_ + h];
        wr[n] = m.x; wi[n] = m.y; gr[n] = m.z; gi[n] = m.w;
        float2 e = states[((size_t)(b * C_ + c) * N_ + n) * H_ + h];
        sr[n] = e.x; si[n] = e.y;
    }
    const float* up = u + ((size_t)b * L_ + (size_t)c * Lc) * H_ + h;
    float* yp = y + ((size_t)b * L_ + (size_t)c * Lc) * H_ + h;
    float uv_next = up[0];
    for (int j = 0; j < Lc; ++j) {
        float uv = uv_next;
        int jn = (j + 1 < Lc) ? (j + 1) : 0;
        uv_next = up[(size_t)jn * H_];
        float acc = 0.0f;
#pragma unroll
        for (int n = 0; n < N_; ++n) {
            float tr = fmaf(wr[n], sr[n], fmaf(-wi[n], si[n], uv));
            float ti = fmaf(wr[n], si[n], wi[n] * sr[n]);
            sr[n] = tr; si[n] = ti;
            acc = fmaf(gr[n], tr, fmaf(gi[n], ti, acc));
        }
        float v = fmaf(Dv, uv, acc);
        float g = 0.5f * v * (1.0f + erff(v * 0.70710678118654752f));
        yp[(size_t)j * H_] = g;
    }
}

// ---------------- launcher ----------------
template <int C_>
static void launch_all(const float* u, const float* log_dt, const float* A_real,
                       const float* A_imag, const float* C_real, const float* C_imag,
                       const float* Dscal, float* y, char* ws, hipStream_t stream) {
    float4* modes = (float4*)ws;                        // H*N*16 = 512 KiB
    float2* wLc   = (float2*)(ws + 524288);             // H*N*8  = 256 KiB
    float2* states = (float2*)(ws + 786432);            // B*C*N*H*8
    int log2Lc = 0;
    for (int v = L_ / C_; v > 1; v >>= 1) ++log2Lc;

    modes_kernel<<<(H_ * N_) / 256, 256, 0, stream>>>(log_dt, A_real, A_imag,
                                                      C_real, C_imag, modes, wLc, log2Lc);
    scan_local<C_><<<(B_ * H_ * C_) / 256, 256, 0, stream>>>(u, modes, states);
    chunk_scan<C_><<<(B_ * N_ * H_) / 256, 256, 0, stream>>>(wLc, states);
    scan_out<C_><<<(B_ * H_ * C_) / 256, 256, 0, stream>>>(u, modes, states, Dscal, y);
}

extern "C" void kernel_launch(void* const* d_in, const int* in_sizes, int n_in,
                              void* d_out, int out_size, void* d_ws, size_t ws_size,
                              hipStream_t stream) {
    const float* u      = (const float*)d_in[0];
    const float* log_dt = (const float*)d_in[1];
    const float* A_real = (const float*)d_in[2];
    const float* A_imag = (const float*)d_in[3];
    const float* C_real = (const float*)d_in[4];
    const float* C_imag = (const float*)d_in[5];
    const float* Dscal  = (const float*)d_in[6];
    float* y = (float*)d_out;
    char* ws = (char*)d_ws;

    const size_t base = 786432;
    auto need = [&](int C) { return base + (size_t)B_ * C * N_ * H_ * 8; };
    if (ws_size >= need(32)) {
        launch_all<32>(u, log_dt, A_real, A_imag, C_real, C_imag, Dscal, y, ws, stream);
    } else if (ws_size >= need(16)) {
        launch_all<16>(u, log_dt, A_real, A_imag, C_real, C_imag, Dscal, y, ws, stream);
    } else {
        launch_all<8>(u, log_dt, A_real, A_imag, C_real, C_imag, Dscal, y, ws, stream);
    }
}

// Round 4
// 637.578 us; speedup vs baseline: 1.0887x; 1.0887x over previous
//
#include <hip/hip_runtime.h>
#include <hip/hip_bf16.h>

// S4D: B=8, L=4096, H=1024, N=32 complex modes. f32 in / f32 out (verified R0-R3).
// Blocked 32-mode complex linear scan. R4: split the 32 modes across lane pairs
// (lane, lane^32) -> 16 modes/lane, halving register pressure (R3: VGPR=148 vs 192
// floats needed -> per-iter reloads, occupancy 11%, VALUBusy 52%). Cross-lane
// combine via __shfl_xor(acc, 32); epilogue on half 0 only.

#define B_ 8
#define L_ 4096
#define H_ 1024
#define N_ 32
#define NH_ 16  // modes per lane (N_/2)

// ---------------- kernel A: per-(h,n) mode constants ----------------
// modes[n*H+h] = (w_r, w_i, g_r, g_i); w = exp(dt*A); g = (2 Re C', -2 Im C');
// C' = (C_r + i C_i)*(w-1)/A.  wLc[n*H+h] = w^(Lc).
__global__ void modes_kernel(const float* __restrict__ log_dt,
                             const float* __restrict__ A_real,
                             const float* __restrict__ A_imag,
                             const float* __restrict__ C_real,
                             const float* __restrict__ C_imag,
                             float4* __restrict__ modes,
                             float2* __restrict__ wLc,
                             int log2Lc) {
    int t = blockIdx.x * blockDim.x + threadIdx.x;
    if (t >= H_ * N_) return;
    int h = t / N_, n = t % N_;
    float dt = expf(log_dt[h]);
    float ar = -expf(A_real[t]);
    float ai = A_imag[t];
    float cr = C_real[t];
    float ci = C_imag[t];
    float dr = ar * dt, di = ai * dt;
    float e = expf(dr);
    float sn, cs;
    sincosf(di, &sn, &cs);
    float wr = e * cs, wi = e * sn;
    float inv = 1.0f / (ar * ar + ai * ai);
    float nr = wr - 1.0f, ni = wi;
    float qr = (nr * ar + ni * ai) * inv;
    float qi = (ni * ar - nr * ai) * inv;
    float gr = 2.0f * (cr * qr - ci * qi);
    float gi = -2.0f * (cr * qi + ci * qr);
    modes[n * H_ + h] = make_float4(wr, wi, gr, gi);
    float pr = wr, pi2 = wi;
    for (int i = 0; i < log2Lc; ++i) {
        float t2r = pr * pr - pi2 * pi2;
        float t2i = 2.0f * pr * pi2;
        pr = t2r; pi2 = t2i;
    }
    wLc[n * H_ + h] = make_float2(pr, pi2);
}

// Decompose: wave w handles (b,c) = w>>5, h-tile = w&31 (32 h per wave).
// lane: half = lane>>5 (mode group), k = lane&31 (h within tile).

// ---------------- kernel B: local scan per chunk (zero entry state) ----------------
template <int C_>
__global__ __launch_bounds__(256) void scan_local(const float* __restrict__ u,
                                                  const float4* __restrict__ modes,
                                                  float2* __restrict__ states) {
    constexpr int Lc = L_ / C_;
    int t = blockIdx.x * blockDim.x + threadIdx.x;
    int lane = t & 63;
    int w = t >> 6;
    int half = lane >> 5;
    int k = lane & 31;
    int h = (w & 31) * 32 + k;
    int bc = w >> 5;
    int c = bc % C_;
    int b = bc / C_;
    int nb = half * NH_;
    float wr[NH_], wi[NH_], sr[NH_], si[NH_];
#pragma unroll
    for (int n = 0; n < NH_; ++n) {
        float4 m = modes[(nb + n) * H_ + h];
        wr[n] = m.x; wi[n] = m.y; sr[n] = 0.0f; si[n] = 0.0f;
    }
    const float* up = u + ((size_t)b * L_ + (size_t)c * Lc) * H_ + h;
    float uv0 = up[0];
    float uv1 = up[H_];
    for (int j = 0; j < Lc; ++j) {
        float uv = uv0;
        uv0 = uv1;
        int j2 = (j + 2 < Lc) ? (j + 2) : 0;  // clamp: avoid OOB prefetch
        uv1 = up[(size_t)j2 * H_];
#pragma unroll
        for (int n = 0; n < NH_; ++n) {
            float tr = fmaf(wr[n], sr[n], fmaf(-wi[n], si[n], uv));
            float ti = fmaf(wr[n], si[n], wi[n] * sr[n]);
            sr[n] = tr; si[n] = ti;
        }
    }
    float2* sp = states + ((size_t)bc * N_ + nb) * H_ + h;
#pragma unroll
    for (int n = 0; n < NH_; ++n) sp[(size_t)n * H_] = make_float2(sr[n], si[n]);
}

// ---------------- kernel C: cross-chunk scan (in place: local-end -> entry) --------
template <int C_>
__global__ __launch_bounds__(256) void chunk_scan(const float2* __restrict__ wLc,
                                                  float2* __restrict__ states) {
    int t = blockIdx.x * blockDim.x + threadIdx.x;
    int h = t % H_;
    int bn = t / H_;
    int n = bn % N_;
    int b = bn / N_;
    float2 wl = wLc[n * H_ + h];
    float er = 0.0f, ei = 0.0f;
    for (int c = 0; c < C_; ++c) {
        float2* p = states + ((size_t)(b * C_ + c) * N_ + n) * H_ + h;
        float2 le = *p;
        *p = make_float2(er, ei);
        float nr2 = fmaf(wl.x, er, fmaf(-wl.y, ei, le.x));
        float ni2 = fmaf(wl.x, ei, fmaf(wl.y, er, le.y));
        er = nr2; ei = ni2;
    }
}

// ---------------- kernel D: re-scan with entry state, emit gelu(y) ----------------
template <int C_>
__global__ __launch_bounds__(256) void scan_out(const float* __restrict__ u,
                                                const float4* __restrict__ modes,
                                                const float2* __restrict__ states,
                                                const float* __restrict__ Dscal,
                                                float* __restrict__ y) {
    constexpr int Lc = L_ / C_;
    int t = blockIdx.x * blockDim.x + threadIdx.x;
    int lane = t & 63;
    int w = t >> 6;
    int half = lane >> 5;
    int k = lane & 31;
    int h = (w & 31) * 32 + k;
    int bc = w >> 5;
    int c = bc % C_;
    int b = bc / C_;
    int nb = half * NH_;
    float Dv = Dscal[0];
    float wr[NH_], wi[NH_], gr[NH_], gi[NH_], sr[NH_], si[NH_];
#pragma unroll
    for (int n = 0; n < NH_; ++n) {
        float4 m = modes[(nb + n) * H_ + h];
        wr[n] = m.x; wi[n] = m.y; gr[n] = m.z; gi[n] = m.w;
        float2 e = states[((size_t)bc * N_ + nb + n) * H_ + h];
        sr[n] = e.x; si[n] = e.y;
    }
    const float* up = u + ((size_t)b * L_ + (size_t)c * Lc) * H_ + h;
    float* yp = y + ((size_t)b * L_ + (size_t)c * Lc) * H_ + h;
    float uv0 = up[0];
    float uv1 = up[H_];
    for (int j = 0; j < Lc; ++j) {
        float uv = uv0;
        uv0 = uv1;
        int j2 = (j + 2 < Lc) ? (j + 2) : 0;
        uv1 = up[(size_t)j2 * H_];
        float acc = 0.0f;
#pragma unroll
        for (int n = 0; n < NH_; ++n) {
            float tr = fmaf(wr[n], sr[n], fmaf(-wi[n], si[n], uv));
            float ti = fmaf(wr[n], si[n], wi[n] * sr[n]);
            sr[n] = tr; si[n] = ti;
            acc = fmaf(gr[n], tr, fmaf(gi[n], ti, acc));
        }
        acc += __shfl_xor(acc, 32, 64);
        if (half == 0) {
            float v = fmaf(Dv, uv, acc);
            float g = 0.5f * v * (1.0f + erff(v * 0.70710678118654752f));
            yp[(size_t)j * H_] = g;
        }
    }
}

// ---------------- launcher ----------------
template <int C_>
static void launch_all(const float* u, const float* log_dt, const float* A_real,
                       const float* A_imag, const float* C_real, const float* C_imag,
                       const float* Dscal, float* y, char* ws, hipStream_t stream) {
    float4* modes = (float4*)ws;                        // H*N*16 = 512 KiB
    float2* wLc   = (float2*)(ws + 524288);             // H*N*8  = 256 KiB
    float2* states = (float2*)(ws + 786432);            // B*C*N*H*8
    int log2Lc = 0;
    for (int v = L_ / C_; v > 1; v >>= 1) ++log2Lc;

    // scan kernels: one wave per (b,c,h-tile of 32), 2 lanes per h (mode halves)
    constexpr int nwaves = B_ * C_ * (H_ / 32);
    constexpr int nblocks = nwaves / 4;  // 4 waves per 256-thread block

    modes_kernel<<<(H_ * N_) / 256, 256, 0, stream>>>(log_dt, A_real, A_imag,
                                                      C_real, C_imag, modes, wLc, log2Lc);
    scan_local<C_><<<nblocks, 256, 0, stream>>>(u, modes, states);
    chunk_scan<C_><<<(B_ * N_ * H_) / 256, 256, 0, stream>>>(wLc, states);
    scan_out<C_><<<nblocks, 256, 0, stream>>>(u, modes, states, Dscal, y);
}

extern "C" void kernel_launch(void* const* d_in, const int* in_sizes, int n_in,
                              void* d_out, int out_size, void* d_ws, size_t ws_size,
                              hipStream_t stream) {
    const float* u      = (const float*)d_in[0];
    const float* log_dt = (const float*)d_in[1];
    const float* A_real = (const float*)d_in[2];
    const float* A_imag = (const float*)d_in[3];
    const float* C_real = (const float*)d_in[4];
    const float* C_imag = (const float*)d_in[5];
    const float* Dscal  = (const float*)d_in[6];
    float* y = (float*)d_out;
    char* ws = (char*)d_ws;

    const size_t base = 786432;
    auto need = [&](int C) { return base + (size_t)B_ * C * N_ * H_ * 8; };
    if (ws_size >= need(32)) {
        launch_all<32>(u, log_dt, A_real, A_imag, C_real, C_imag, Dscal, y, ws, stream);
    } else if (ws_size >= need(16)) {
        launch_all<16>(u, log_dt, A_real, A_imag, C_real, C_imag, Dscal, y, ws, stream);
    } else {
        launch_all<8>(u, log_dt, A_real, A_imag, C_real, C_imag, Dscal, y, ws, stream);
    }
}